// Round 2
// baseline (407.880 us; speedup 1.0000x reference)
//
#include <hip/hip_runtime.h>
#include <stdint.h>

// Problem constants
#define B_SZ 1024
#define Z_SZ 32768
#define D_SZ 128
#define NZ   32                 // z chunks (split-Z)
#define CZ   (Z_SZ / NZ)        // 1024 z per chunk
#define TZ   64                 // z per inner tile
#define ITERS (CZ / TZ)         // 16
#define TBLK 64                 // batch rows per block (4 waves x 16)
#define WROWS 16                // batch rows per wave

#define SP_STRIDE    72         // 16 x 72 bf16 per wave (P tile), 144B rows

// Workspace layout (float units)
#define WS_O    0                               // [NZ][B][D] fp32 partial O
#define WS_M    (NZ * B_SZ * D_SZ)              // [NZ][B]
#define WS_L    (WS_M + NZ * B_SZ)
#define WS_C    (WS_L + NZ * B_SZ)
#define WS_EB_F (WS_C + NZ * B_SZ)              // bf16 embB [Z][D] (Z*D ushorts = Z*D/2 floats)
#define WS_ET_F (WS_EB_F + (Z_SZ * D_SZ / 2))   // bf16 embT [D][Z]
// total = WS_ET_F + Z*D/2 floats  ~= 33.9 MB

typedef short bf16x8 __attribute__((ext_vector_type(8)));
typedef float f32x4  __attribute__((ext_vector_type(4)));

__device__ __forceinline__ unsigned short f2bf(float f) {
    union { float f; uint32_t u; } v; v.f = f;
    uint32_t u = v.u;
    u = (u + 0x7FFFu + ((u >> 16) & 1u)) >> 16;   // RNE truncate to bf16
    return (unsigned short)u;
}

// ---- one-shot fp32 -> bf16 table conversion (row-major + transposed) ----
__global__ __launch_bounds__(256) void convert_emb(
    const float* __restrict__ emb,
    unsigned short* __restrict__ embB,
    unsigned short* __restrict__ embT)
{
    __shared__ unsigned short s[128 * 68];   // [d][z_local], pad 68 to break conflicts
    const int tid = threadIdx.x;
    const int z0  = blockIdx.x * 64;
    const int zl  = tid >> 2;                // 0..63
    const int ds  = (tid & 3) * 32;          // d segment
    const float* src = emb + (size_t)(z0 + zl) * D_SZ + ds;
    unsigned short* dstB = embB + (size_t)(z0 + zl) * D_SZ + ds;
#pragma unroll
    for (int u = 0; u < 8; ++u) {
        float4 x = *(const float4*)(src + 4 * u);
        ushort4 h; h.x = f2bf(x.x); h.y = f2bf(x.y); h.z = f2bf(x.z); h.w = f2bf(x.w);
        *(ushort4*)(dstB + 4 * u) = h;       // coalesced bf16 row-major write
        s[(ds + 4*u + 0) * 68 + zl] = h.x;
        s[(ds + 4*u + 1) * 68 + zl] = h.y;
        s[(ds + 4*u + 2) * 68 + zl] = h.z;
        s[(ds + 4*u + 3) * 68 + zl] = h.w;
    }
    __syncthreads();
    const int d  = tid >> 1;                 // 0..127
    const int zh = (tid & 1) * 32;
    unsigned short* dstT = embT + (size_t)d * Z_SZ + z0 + zh;
    const unsigned short* srow = s + d * 68 + zh;
#pragma unroll
    for (int u = 0; u < 8; ++u) {            // 32 ushorts = 8 x ushort4 (8B aligned: 136*d)
        *(ushort4*)(dstT + 4 * u) = *(const ushort4*)(srow + 4 * u);
    }
}

// ---- barrier-free flash-style partial kernel ----
__global__ __launch_bounds__(256, 2) void attn_part(
    const int*            __restrict__ zs,
    const float*          __restrict__ ctx,
    const unsigned short* __restrict__ embB,
    const unsigned short* __restrict__ embT,
    float*                __restrict__ ws)
{
    __shared__ __align__(16) unsigned short s_P[4 * WROWS * SP_STRIDE];  // 9216 B, per-wave slices

    const int tid  = threadIdx.x;
    const int wave = tid >> 6;
    const int lane = tid & 63;
    const int l15  = lane & 15;
    const int quad = lane >> 4;

    const int bg     = blockIdx.x;            // 0..15 batch group
    const int ch     = blockIdx.y;            // 0..31 z-chunk
    const int z_base = ch * CZ;
    const int wb0    = bg * TBLK + wave * WROWS;

    // ---- ctx A-fragments, scaled by 1/sqrt(D), in registers whole kernel ----
    bf16x8 afrag[4];
    {
        const float scale = 0.08838834764831845f;  // 1/sqrt(128)
        const float* crow = ctx + (size_t)(wb0 + l15) * D_SZ;
#pragma unroll
        for (int ks = 0; ks < 4; ++ks) {
            const float* p = crow + ks * 32 + quad * 8;
            float4 x0 = *(const float4*)(p);
            float4 x1 = *(const float4*)(p + 4);
            bf16x8 a;
            a[0] = (short)f2bf(x0.x * scale); a[1] = (short)f2bf(x0.y * scale);
            a[2] = (short)f2bf(x0.z * scale); a[3] = (short)f2bf(x0.w * scale);
            a[4] = (short)f2bf(x1.x * scale); a[5] = (short)f2bf(x1.y * scale);
            a[6] = (short)f2bf(x1.z * scale); a[7] = (short)f2bf(x1.w * scale);
            afrag[ks] = a;
        }
    }

    float m_r[4], l_r[4];
    int   cnt_r[4];
    f32x4 acc2[8];
#pragma unroll
    for (int r = 0; r < 4; ++r) { m_r[r] = -1e30f; l_r[r] = 0.f; cnt_r[r] = 0; }
#pragma unroll
    for (int n = 0; n < 8; ++n) { acc2[n][0]=0.f; acc2[n][1]=0.f; acc2[n][2]=0.f; acc2[n][3]=0.f; }

    unsigned short* pw = s_P + wave * (WROWS * SP_STRIDE);

    for (int it = 0; it < ITERS; ++it) {
        const int z0 = z_base + it * TZ;

        // ---- mask bits: msk[nt][r] = z_sparse[wb0+quad*4+r][z0+nt*16+l15] > 0 ----
        int msk[4][4];
#pragma unroll
        for (int r = 0; r < 4; ++r) {
            const int b = wb0 + quad * 4 + r;
            const int* p = zs + (size_t)b * Z_SZ + z0 + l15;
#pragma unroll
            for (int nt = 0; nt < 4; ++nt) msk[nt][r] = (p[nt * 16] > 0) ? 1 : 0;
            cnt_r[r] += msk[0][r] + msk[1][r] + msk[2][r] + msk[3][r];
        }

        // ---- GEMM1: S[16 x 64] = ctx @ embB_tile^T, B-frags direct from global ----
        f32x4 sfr[4];
#pragma unroll
        for (int nt = 0; nt < 4; ++nt) {
            f32x4 c; c[0]=0.f; c[1]=0.f; c[2]=0.f; c[3]=0.f;
            const unsigned short* bb = embB + (size_t)(z0 + nt * 16 + l15) * D_SZ + quad * 8;
#pragma unroll
            for (int ks = 0; ks < 4; ++ks) {
                bf16x8 bf = *(const bf16x8*)(bb + ks * 32);
                c = __builtin_amdgcn_mfma_f32_16x16x32_bf16(afrag[ks], bf, c, 0, 0, 0);
            }
            sfr[nt] = c;
        }

        // ---- masked online softmax ----
        float tmax[4];
#pragma unroll
        for (int r = 0; r < 4; ++r) {
            float a0 = msk[0][r] ? sfr[0][r] : -1e30f;
            float a1 = msk[1][r] ? sfr[1][r] : -1e30f;
            float a2 = msk[2][r] ? sfr[2][r] : -1e30f;
            float a3 = msk[3][r] ? sfr[3][r] : -1e30f;
            tmax[r] = fmaxf(fmaxf(a0, a1), fmaxf(a2, a3));
        }
#pragma unroll
        for (int s = 1; s < 16; s <<= 1) {
#pragma unroll
            for (int r = 0; r < 4; ++r) tmax[r] = fmaxf(tmax[r], __shfl_xor(tmax[r], s));
        }
        float alpha[4];
#pragma unroll
        for (int r = 0; r < 4; ++r) {
            float mnew = fmaxf(m_r[r], tmax[r]);
            alpha[r] = __expf(m_r[r] - mnew);
            m_r[r] = mnew;
            l_r[r] *= alpha[r];
        }
        float psum[4]; psum[0]=0.f; psum[1]=0.f; psum[2]=0.f; psum[3]=0.f;
#pragma unroll
        for (int nt = 0; nt < 4; ++nt) {
#pragma unroll
            for (int r = 0; r < 4; ++r) {
                float p = msk[nt][r] ? __expf(sfr[nt][r] - m_r[r]) : 0.f;
                psum[r] += p;
                pw[(quad * 4 + r) * SP_STRIDE + nt * 16 + l15] = f2bf(p);
            }
        }
#pragma unroll
        for (int s = 1; s < 16; s <<= 1) {
#pragma unroll
            for (int r = 0; r < 4; ++r) psum[r] += __shfl_xor(psum[r], s);
        }
#pragma unroll
        for (int r = 0; r < 4; ++r) l_r[r] += psum[r];

#pragma unroll
        for (int n = 0; n < 8; ++n) {
#pragma unroll
            for (int r = 0; r < 4; ++r) acc2[n][r] *= alpha[r];
        }

        // ---- GEMM2: O[16 x 128] += P[16 x 64] @ emb_tile[64 x 128], B-frags from embT ----
        const unsigned short* pb = pw + l15 * SP_STRIDE + quad * 8;
        bf16x8 pA0 = *(const bf16x8*)(pb);        // same-wave ds_write->ds_read, no barrier needed
        bf16x8 pA1 = *(const bf16x8*)(pb + 32);
#pragma unroll
        for (int nt2 = 0; nt2 < 8; ++nt2) {
            const unsigned short* tb = embT + (size_t)(nt2 * 16 + l15) * Z_SZ + z0 + quad * 8;
            bf16x8 b0 = *(const bf16x8*)(tb);
            bf16x8 b1 = *(const bf16x8*)(tb + 32);
            acc2[nt2] = __builtin_amdgcn_mfma_f32_16x16x32_bf16(pA0, b0, acc2[nt2], 0, 0, 0);
            acc2[nt2] = __builtin_amdgcn_mfma_f32_16x16x32_bf16(pA1, b1, acc2[nt2], 0, 0, 0);
        }
    }

    // ---- epilogue ----
#pragma unroll
    for (int nt2 = 0; nt2 < 8; ++nt2) {
#pragma unroll
        for (int r = 0; r < 4; ++r) {
            const int b = wb0 + quad * 4 + r;
            ws[WS_O + ((size_t)ch * B_SZ + b) * D_SZ + nt2 * 16 + l15] = acc2[nt2][r];
        }
    }
    float cntf[4];
#pragma unroll
    for (int r = 0; r < 4; ++r) cntf[r] = (float)cnt_r[r];
#pragma unroll
    for (int s = 1; s < 16; s <<= 1) {
#pragma unroll
        for (int r = 0; r < 4; ++r) cntf[r] += __shfl_xor(cntf[r], s);
    }
    if (l15 == 0) {
#pragma unroll
        for (int r = 0; r < 4; ++r) {
            const int b = wb0 + quad * 4 + r;
            ws[WS_M + ch * B_SZ + b] = m_r[r];
            ws[WS_L + ch * B_SZ + b] = l_r[r];
            ws[WS_C + ch * B_SZ + b] = cntf[r];
        }
    }
}

__global__ __launch_bounds__(256) void attn_reduce(
    const float* __restrict__ ws, float* __restrict__ out)
{
    const int b = blockIdx.x * 2 + (threadIdx.x >> 7);
    const int d = threadIdx.x & 127;
    const float* mP = ws + WS_M;
    const float* lP = ws + WS_L;
    const float* cP = ws + WS_C;

    float M = -1e30f;
#pragma unroll
    for (int c = 0; c < NZ; ++c) M = fmaxf(M, mP[c * B_SZ + b]);

    float L = 0.f, C = 0.f, acc = 0.f;
#pragma unroll
    for (int c = 0; c < NZ; ++c) {
        float w = __expf(mP[c * B_SZ + b] - M);
        L += lP[c * B_SZ + b] * w;
        C += cP[c * B_SZ + b];
        acc += ws[WS_O + ((size_t)c * B_SZ + b) * D_SZ + d] * w;
    }
    float cnt = fmaxf(C, 1.0f);
    out[(size_t)b * D_SZ + d] = (L > 0.f) ? acc / (L * cnt) : 0.f;
}

extern "C" void kernel_launch(void* const* d_in, const int* in_sizes, int n_in,
                              void* d_out, int out_size, void* d_ws, size_t ws_size,
                              hipStream_t stream) {
    (void)in_sizes; (void)n_in; (void)out_size; (void)ws_size;
    const int*   zs  = (const int*)  d_in[0];
    const float* ctx = (const float*)d_in[1];
    const float* emb = (const float*)d_in[2];
    float* out = (float*)d_out;
    float* ws  = (float*)d_ws;

    unsigned short* embB = (unsigned short*)(ws + WS_EB_F);
    unsigned short* embT = (unsigned short*)(ws + WS_ET_F);

    convert_emb<<<Z_SZ / 64, 256, 0, stream>>>(emb, embB, embT);

    dim3 grid1(B_SZ / TBLK, NZ);   // (16, 32)
    attn_part<<<grid1, 256, 0, stream>>>(zs, ctx, embB, embT, ws);

    attn_reduce<<<B_SZ / 2, 256, 0, stream>>>(ws, out);
}

// Round 3
// 330.370 us; speedup vs baseline: 1.2346x; 1.2346x over previous
//
#include <hip/hip_runtime.h>
#include <stdint.h>

// Problem constants
#define B_SZ 1024
#define Z_SZ 32768
#define D_SZ 128
#define TZ   64                 // z per inner tile
#define TBLK 64                 // batch rows per block (4 waves x 16)
#define WROWS 16

typedef short bf16x8 __attribute__((ext_vector_type(8)));
typedef float f32x4  __attribute__((ext_vector_type(4)));

__device__ __forceinline__ unsigned short f2bf(float f) {
    union { float f; uint32_t u; } v; v.f = f;
    uint32_t u = v.u;
    u = (u + 0x7FFFu + ((u >> 16) & 1u)) >> 16;   // RNE truncate to bf16
    return (unsigned short)u;
}

// ---- one-shot fp32 -> bf16: embB row-major [Z][128]; embT2 blocked-transposed [Z/64][128][64] ----
__global__ __launch_bounds__(256) void convert_emb(
    const float* __restrict__ emb,
    unsigned short* __restrict__ embB,
    unsigned short* __restrict__ embT2)
{
    __shared__ unsigned short s[128 * 68];   // [d][z_local], pad 68
    const int tid = threadIdx.x;
    const int z0  = blockIdx.x * 64;
    const int zl  = tid >> 2;                // 0..63
    const int ds  = (tid & 3) * 32;          // d segment
    const float* src = emb + (size_t)(z0 + zl) * D_SZ + ds;
    unsigned short* dstB = embB + (size_t)(z0 + zl) * D_SZ + ds;
#pragma unroll
    for (int u = 0; u < 8; ++u) {
        float4 x = *(const float4*)(src + 4 * u);
        ushort4 h; h.x = f2bf(x.x); h.y = f2bf(x.y); h.z = f2bf(x.z); h.w = f2bf(x.w);
        *(ushort4*)(dstB + 4 * u) = h;
        s[(ds + 4*u + 0) * 68 + zl] = h.x;
        s[(ds + 4*u + 1) * 68 + zl] = h.y;
        s[(ds + 4*u + 2) * 68 + zl] = h.z;
        s[(ds + 4*u + 3) * 68 + zl] = h.w;
    }
    __syncthreads();
    const int d  = tid & 127;                // consecutive tid -> consecutive d rows (coalesced-ish)
    const int zh = (tid >> 7) * 32;
    unsigned short* dstT = embT2 + (size_t)blockIdx.x * (128 * 64) + d * 64 + zh;
    const unsigned short* srow = s + d * 68 + zh;
#pragma unroll
    for (int u = 0; u < 8; ++u)
        *(ushort4*)(dstT + 4 * u) = *(const ushort4*)(srow + 4 * u);
}

// ---- flash-style partial kernel: LDS tiles, XOR-swizzled (no padding, 40960 B total) ----
// s_all layout (short units): [0,8192) s_emb 64x128 (row z, 16 segs of 8sh, phys=seg^ (z&15))
//                             [8192,16384) s_embT 128x64 (row d, 8 segs, phys=seg^(d&7))
//                             [16384,20480) s_P 4 waves x 16x64 (row b, 8 segs, phys=seg^(row&7))
__global__ __launch_bounds__(256, 4) void attn_part(
    const int*            __restrict__ zs,
    const float*          __restrict__ ctx,
    const unsigned short* __restrict__ embB,
    const unsigned short* __restrict__ embT2,
    float* __restrict__ mbuf, float* __restrict__ lbuf,
    float* __restrict__ cbuf, float* __restrict__ obuf,
    int iters)
{
    __shared__ __align__(16) unsigned short s_all[20480];   // 40960 B -> 4 blocks/CU

    const int tid  = threadIdx.x;
    const int wave = tid >> 6;
    const int lane = tid & 63;
    const int l15  = lane & 15;
    const int quad = lane >> 4;

    const int bg     = blockIdx.x;                 // 0..15
    const int ch     = blockIdx.y;                 // 0..nz-1
    const int cz     = iters * TZ;
    const int z_base = ch * cz;
    const int wb0    = bg * TBLK + wave * WROWS;

    // ---- ctx A-fragments (scaled), in registers whole kernel ----
    bf16x8 afrag[4];
    {
        const float scale = 0.08838834764831845f;  // 1/sqrt(128)
        const float* crow = ctx + (size_t)(wb0 + l15) * D_SZ;
#pragma unroll
        for (int ks = 0; ks < 4; ++ks) {
            const float* p = crow + ks * 32 + quad * 8;
            float4 x0 = *(const float4*)(p);
            float4 x1 = *(const float4*)(p + 4);
            bf16x8 a;
            a[0] = (short)f2bf(x0.x * scale); a[1] = (short)f2bf(x0.y * scale);
            a[2] = (short)f2bf(x0.z * scale); a[3] = (short)f2bf(x0.w * scale);
            a[4] = (short)f2bf(x1.x * scale); a[5] = (short)f2bf(x1.y * scale);
            a[6] = (short)f2bf(x1.z * scale); a[7] = (short)f2bf(x1.w * scale);
            afrag[ks] = a;
        }
    }

    float m_r[4], l_r[4];
    int   cnt_r[4];
    f32x4 acc2[8];
#pragma unroll
    for (int r = 0; r < 4; ++r) { m_r[r] = -1e30f; l_r[r] = 0.f; cnt_r[r] = 0; }
#pragma unroll
    for (int n = 0; n < 8; ++n) { acc2[n][0]=0.f; acc2[n][1]=0.f; acc2[n][2]=0.f; acc2[n][3]=0.f; }

    unsigned short* pw = s_all + 16384 + wave * 1024;   // per-wave P slice

    for (int it = 0; it < iters; ++it) {
        const int z0 = z_base + it * TZ;

        __syncthreads();   // previous tile's LDS reads complete

        // ---- stage s_emb: 16 KB contiguous global stream, swizzled LDS write ----
#pragma unroll
        for (int k = 0; k < 4; ++k) {
            int c   = tid + 256 * k;               // 16B chunk id, 0..1023
            int row = c >> 4, lseg = c & 15;
            bf16x8 v = *(const bf16x8*)(embB + ((size_t)(z0 + row) << 7) + (lseg << 3));
            int phys = lseg ^ (row & 15);
            *(bf16x8*)(s_all + (row << 7) + (phys << 3)) = v;
        }
        // ---- stage s_embT from blocked table: fully contiguous 16 KB global read ----
        {
            const unsigned short* tbase = embT2 + ((size_t)(z0 >> 6)) * (128 * 64);
#pragma unroll
            for (int k = 0; k < 4; ++k) {
                int c = tid + 256 * k;             // 0..1023
                int d = c >> 3, lseg = c & 7;
                bf16x8 v = *(const bf16x8*)(tbase + ((size_t)c << 3));
                int phys = lseg ^ (d & 7);
                *(bf16x8*)(s_all + 8192 + (d << 6) + (phys << 3)) = v;
            }
        }

        // ---- packed mask bits: bit nt of mbits[r] = z_sparse[wb0+quad*4+r][z0+nt*16+l15] > 0 ----
        unsigned mbits[4];
#pragma unroll
        for (int r = 0; r < 4; ++r) {
            const int* p = zs + (size_t)(wb0 + quad * 4 + r) * Z_SZ + z0 + l15;
            unsigned m = 0;
#pragma unroll
            for (int nt = 0; nt < 4; ++nt) m |= (unsigned)(p[nt * 16] > 0) << nt;
            mbits[r] = m;
            cnt_r[r] += __popc(m);
        }

        __syncthreads();   // staging visible

        // ---- GEMM1: S[16x64] = ctx @ emb_tile^T (K=128), swizzled reads (conflict-free) ----
        f32x4 sfr[4];
#pragma unroll
        for (int nt = 0; nt < 4; ++nt) {
            f32x4 c; c[0]=0.f; c[1]=0.f; c[2]=0.f; c[3]=0.f;
            const unsigned short* bb = s_all + ((nt * 16 + l15) << 7);
#pragma unroll
            for (int ks = 0; ks < 4; ++ks) {
                int phys = ((ks << 2) | quad) ^ l15;
                bf16x8 bf = *(const bf16x8*)(bb + (phys << 3));
                c = __builtin_amdgcn_mfma_f32_16x16x32_bf16(afrag[ks], bf, c, 0, 0, 0);
            }
            sfr[nt] = c;
        }

        // ---- masked online softmax ----
        float tmax[4];
#pragma unroll
        for (int r = 0; r < 4; ++r) {
            float a0 = (mbits[r] & 1u) ? sfr[0][r] : -1e30f;
            float a1 = (mbits[r] & 2u) ? sfr[1][r] : -1e30f;
            float a2 = (mbits[r] & 4u) ? sfr[2][r] : -1e30f;
            float a3 = (mbits[r] & 8u) ? sfr[3][r] : -1e30f;
            tmax[r] = fmaxf(fmaxf(a0, a1), fmaxf(a2, a3));
        }
#pragma unroll
        for (int s = 1; s < 16; s <<= 1) {
#pragma unroll
            for (int r = 0; r < 4; ++r) tmax[r] = fmaxf(tmax[r], __shfl_xor(tmax[r], s));
        }
        float alpha[4];
#pragma unroll
        for (int r = 0; r < 4; ++r) {
            float mnew = fmaxf(m_r[r], tmax[r]);
            alpha[r] = __expf(m_r[r] - mnew);
            m_r[r] = mnew;
            l_r[r] *= alpha[r];
        }
        float psum[4]; psum[0]=0.f; psum[1]=0.f; psum[2]=0.f; psum[3]=0.f;
#pragma unroll
        for (int nt = 0; nt < 4; ++nt) {
#pragma unroll
            for (int r = 0; r < 4; ++r) {
                float p = ((mbits[r] >> nt) & 1u) ? __expf(sfr[nt][r] - m_r[r]) : 0.f;
                psum[r] += p;
                int row  = quad * 4 + r;
                int seg  = nt * 2 + (l15 >> 3);
                int phys = seg ^ (row & 7);
                pw[(row << 6) + (phys << 3) + (l15 & 7)] = f2bf(p);
            }
        }
#pragma unroll
        for (int s = 1; s < 16; s <<= 1) {
#pragma unroll
            for (int r = 0; r < 4; ++r) psum[r] += __shfl_xor(psum[r], s);
        }
#pragma unroll
        for (int r = 0; r < 4; ++r) l_r[r] += psum[r];

#pragma unroll
        for (int n = 0; n < 8; ++n) {
#pragma unroll
            for (int r = 0; r < 4; ++r) acc2[n][r] *= alpha[r];
        }

        // ---- GEMM2: O[16x128] += P[16x64] @ emb_tile[64x128], swizzled reads ----
        const unsigned short* pb = pw + (l15 << 6);
        const int x0 = ( quad      ^ (l15 & 7)) << 3;
        const int x1 = ((quad + 4) ^ (l15 & 7)) << 3;
        bf16x8 pA0 = *(const bf16x8*)(pb + x0);   // same-wave ds_write->ds_read, compiler orders
        bf16x8 pA1 = *(const bf16x8*)(pb + x1);
#pragma unroll
        for (int nt2 = 0; nt2 < 8; ++nt2) {
            const unsigned short* tb = s_all + 8192 + ((nt2 * 16 + l15) << 6);
            bf16x8 b0 = *(const bf16x8*)(tb + x0);
            bf16x8 b1 = *(const bf16x8*)(tb + x1);
            acc2[nt2] = __builtin_amdgcn_mfma_f32_16x16x32_bf16(pA0, b0, acc2[nt2], 0, 0, 0);
            acc2[nt2] = __builtin_amdgcn_mfma_f32_16x16x32_bf16(pA1, b1, acc2[nt2], 0, 0, 0);
        }
    }

    // ---- epilogue ----
#pragma unroll
    for (int nt2 = 0; nt2 < 8; ++nt2) {
#pragma unroll
        for (int r = 0; r < 4; ++r) {
            const int b = wb0 + quad * 4 + r;
            obuf[((size_t)ch * B_SZ + b) * D_SZ + nt2 * 16 + l15] = acc2[nt2][r];
        }
    }
    float cntf[4];
#pragma unroll
    for (int r = 0; r < 4; ++r) cntf[r] = (float)cnt_r[r];
#pragma unroll
    for (int s = 1; s < 16; s <<= 1) {
#pragma unroll
        for (int r = 0; r < 4; ++r) cntf[r] += __shfl_xor(cntf[r], s);
    }
    if (l15 == 0) {
#pragma unroll
        for (int r = 0; r < 4; ++r) {
            const int b = wb0 + quad * 4 + r;
            mbuf[ch * B_SZ + b] = m_r[r];
            lbuf[ch * B_SZ + b] = l_r[r];
            cbuf[ch * B_SZ + b] = cntf[r];
        }
    }
}

__global__ __launch_bounds__(256) void attn_reduce(
    const float* __restrict__ mbuf, const float* __restrict__ lbuf,
    const float* __restrict__ cbuf, const float* __restrict__ obuf,
    float* __restrict__ out, int nz)
{
    const int b = blockIdx.x * 2 + (threadIdx.x >> 7);
    const int d = threadIdx.x & 127;

    float M = -1e30f;
    for (int c = 0; c < nz; ++c) M = fmaxf(M, mbuf[c * B_SZ + b]);

    float L = 0.f, C = 0.f, acc = 0.f;
    for (int c = 0; c < nz; ++c) {
        float w = __expf(mbuf[c * B_SZ + b] - M);
        L += lbuf[c * B_SZ + b] * w;
        C += cbuf[c * B_SZ + b];
        acc += obuf[((size_t)c * B_SZ + b) * D_SZ + d] * w;
    }
    float cnt = fmaxf(C, 1.0f);
    out[(size_t)b * D_SZ + d] = (L > 0.f) ? acc / (L * cnt) : 0.f;
}

extern "C" void kernel_launch(void* const* d_in, const int* in_sizes, int n_in,
                              void* d_out, int out_size, void* d_ws, size_t ws_size,
                              hipStream_t stream) {
    (void)in_sizes; (void)n_in; (void)out_size;
    const int*   zs  = (const int*)  d_in[0];
    const float* ctx = (const float*)d_in[1];
    const float* emb = (const float*)d_in[2];
    float* out = (float*)d_out;
    float* wsf = (float*)d_ws;

    const size_t EMB_FL = (size_t)Z_SZ * D_SZ / 2;   // bf16 table in float units
    // pick nz by available workspace (ws_size is constant across calls -> same work every call)
    int nz = 64;
    {
        size_t need64 = (2 * EMB_FL + (size_t)64 * B_SZ * (3 + D_SZ)) * 4;
        if (ws_size < need64) nz = 32;
    }
    const int iters = (Z_SZ / nz) / TZ;

    unsigned short* embB  = (unsigned short*)wsf;
    unsigned short* embT2 = (unsigned short*)(wsf + EMB_FL);
    float* mbuf = wsf + 2 * EMB_FL;
    float* lbuf = mbuf + (size_t)nz * B_SZ;
    float* cbuf = lbuf + (size_t)nz * B_SZ;
    float* obuf = cbuf + (size_t)nz * B_SZ;

    convert_emb<<<Z_SZ / 64, 256, 0, stream>>>(emb, embB, embT2);

    dim3 grid1(B_SZ / TBLK, nz);   // (16, nz): x-fastest -> blocks sharing a chunk adjacent (L2)
    attn_part<<<grid1, 256, 0, stream>>>(zs, ctx, embB, embT2, mbuf, lbuf, cbuf, obuf, iters);

    attn_reduce<<<B_SZ / 2, 256, 0, stream>>>(mbuf, lbuf, cbuf, obuf, out, nz);
}